// Round 15
// baseline (190.791 us; speedup 1.0000x reference)
//
#include <hip/hip_runtime.h>

typedef unsigned short u16;
typedef unsigned int u32;
typedef unsigned long long u64;
typedef __attribute__((ext_vector_type(8))) short bfrag;  // 8 bf16 (4 VGPRs)
typedef __attribute__((ext_vector_type(4))) short sfrag;  // 4 bf16 (2 VGPRs)
typedef __attribute__((ext_vector_type(4))) float ffrag;  // 4 fp32

// B=256, L=200, D=256, H=16, Dh=16, M=51200
// Head-major slice: [B,H,slot,16], slice stride 3200 u16, b-stride 51200 u16.
// COMPACT convention: per batch b, slot i (i<cnt_b) = i-th UNMASKED l
// (ascending). cnt_b==0 -> identity map over all 200 (matches reference's
// shift-invariant softmax / uniform pool). Slots >= cnt_b are never written;
// reads are clamped to slot<cnt so uninitialized memory never propagates.

__device__ __forceinline__ float bf2f(u16 u) {
    union { float f; u32 i; } c; c.i = ((u32)u) << 16; return c.f;
}
__device__ __forceinline__ u16 f2bf(float f) {           // RNE
    union { float f; u32 i; } c; c.f = f;
    u32 r = c.i + 0x7FFFu + ((c.i >> 16) & 1u);
    return (u16)(r >> 16);
}
__device__ __forceinline__ u32 pack2bf(float lo, float hi) {  // RNE pair
    union { float f; u32 i; } a, b; a.f = lo; b.f = hi;
    u32 ra = a.i + 0x7FFFu + ((a.i >> 16) & 1u);
    u32 rb = b.i + 0x7FFFu + ((b.i >> 16) & 1u);
    return (ra >> 16) | (rb & 0xFFFF0000u);
}
__device__ __forceinline__ ffrag mfma16(bfrag a, bfrag b, ffrag c) {
    return __builtin_amdgcn_mfma_f32_16x16x32_bf16(a, b, c, 0, 0, 0);
}
__device__ __forceinline__ ffrag mfma16k16(sfrag a, sfrag b, ffrag c) {
    return __builtin_amdgcn_mfma_f32_16x16x16bf16_1k(a, b, c, 0, 0, 0);
}
// Async global->LDS, 16B per lane. LDS dest = wave-uniform base + lane*16.
__device__ __forceinline__ void gload16(const u16* g, u16* l) {
    __builtin_amdgcn_global_load_lds(
        (const __attribute__((address_space(1))) u32*)g,
        (__attribute__((address_space(3))) u32*)l, 16, 0, 0);
}

// ---------------------------------------------------------------------------
// LDS-tiled transpose+cast: W[k][n] f32 -> Wt[n][k] bf16, 4 matrices.
// ---------------------------------------------------------------------------
__global__ __launch_bounds__(256) void wtrans_k(
    const float* __restrict__ W0, const float* __restrict__ W1,
    const float* __restrict__ W2, const float* __restrict__ W3,
    u16* __restrict__ Wt)
{
    __shared__ u16 t_s[64][72];
    const int mat = blockIdx.z;
    const float* W = (mat == 0) ? W0 : (mat == 1) ? W1 : (mat == 2) ? W2 : W3;
    const int k0 = blockIdx.x * 64, n0 = blockIdx.y * 64;
    const int r = threadIdx.x >> 2, cq = threadIdx.x & 3;

    const float* src = W + (size_t)(k0 + r) * 256 + n0 + cq * 16;
#pragma unroll
    for (int j = 0; j < 16; j += 4) {
        float4 f = *(const float4*)(src + j);
        t_s[cq * 16 + j + 0][r] = f2bf(f.x);
        t_s[cq * 16 + j + 1][r] = f2bf(f.y);
        t_s[cq * 16 + j + 2][r] = f2bf(f.z);
        t_s[cq * 16 + j + 3][r] = f2bf(f.w);
    }
    __syncthreads();
    u16* dst = Wt + ((size_t)mat * 256 + n0 + r) * 256 + k0 + cq * 16;
    *(bfrag*)(dst)     = *(const bfrag*)&t_s[r][cq * 16];
    *(bfrag*)(dst + 8) = *(const bfrag*)&t_s[r][cq * 16 + 8];
}

// ---------------------------------------------------------------------------
// GEMM v11: v9 (proven r8-r13) with B staged via global_load_lds width=16.
//   - LDS dest LINEAR (wave-uniform base + lane*16); the XOR swizzle is
//     pre-applied to the per-lane GLOBAL source row (row = slot ^ (plane<<2)),
//     so the read path and stored bits are IDENTICAL to v9 (rule 21: swizzle
//     both-sides-or-neither -> here source-permutation == read-permutation).
//   - 8 waves x 2 gloads cover 4 planes x 256 slots (1 KB per gload).
//   - Removes B's VGPR transit + ds_writes from the 2-barrier stage window;
//     DMA is drained by the existing __syncthreads (vmcnt(0) semantics).
//   - A-staging (f32 gather + RNE pack) unchanged. Numerics unchanged.
// grid (256, 3). Chunk loop handles cnt>128.
// (BK=64 variant REJECTED r12: failed replay-determinism tripwire.)
// ---------------------------------------------------------------------------
__global__ __launch_bounds__(512) void gemm_k(
    const void* __restrict__ Avp, const u16* __restrict__ Wtp,
    const int* __restrict__ msk,
    const float* __restrict__ b0, const float* __restrict__ b1,
    const float* __restrict__ b2,
    u16* __restrict__ o0, u16* __restrict__ o1, u16* __restrict__ o2)
{
    const int b     = blockIdx.x;          // 0..255
    const int matid = blockIdx.y;          // 0=Q 1=K 2=V
    const int tid = threadIdx.x;
    const int wave = tid >> 6, lane = tid & 63;
    const int quad = lane >> 4, l16 = lane & 15;
    const int wm = wave >> 1, wn = wave & 1;   // 4x2 wave grid

    __shared__ __align__(16) u16 a_s[4][128][8];   //  8 KB
    __shared__ __align__(16) u16 b_s[4][256][8];   // 16 KB
    __shared__ u16 idx_s[200];
    __shared__ int wcnt_s[8];

    int m = 0;
    if (tid < 200) m = (msk[b * 200 + tid] != 0) ? 1 : 0;
    u64 bal = __ballot(m);
    if (lane == 0) wcnt_s[wave] = __popcll(bal);
    __syncthreads();
    int cnt = 0;
#pragma unroll
    for (int w = 0; w < 8; w++) cnt += wcnt_s[w];
    if (cnt == 0) {
        if (tid < 200) idx_s[tid] = (u16)tid;
    } else if (m) {
        int woff = 0;
        for (int w = 0; w < wave; w++) woff += wcnt_s[w];
        idx_s[woff + __popcll(bal & ((1ull << lane) - 1ull))] = (u16)tid;
    }
    __syncthreads();
    if (cnt == 0) cnt = 200;

    const float* Af = (const float*)Avp;

    const int sr = tid >> 2;               // 0..127
    const int sc = tid & 3;                // k-octet 0..3 (A staging)

    // ---- B gload sources: wave w stages plane bp = w>>1, slot quarters
    // bq*64..bq*64+63 and (bq+1)*64..: slot s of plane p holds W row
    // (s ^ (p<<2)) at k-octet p (XOR involution == v9's write mapping).
    const int bp = wave >> 1;              // plane (k-octet) 0..3
    const int bq = (wave & 1) * 2;         // first quarter of this wave
    const int row0 = ((bq    ) * 64 + lane) ^ (bp << 2);
    const int row1 = ((bq + 1) * 64 + lane) ^ (bp << 2);
    const u16* wsrc0 = Wtp + (size_t)(matid * 256 + row0) * 256 + bp * 8;
    const u16* wsrc1 = Wtp + (size_t)(matid * 256 + row1) * 256 + bp * 8;
    u16* bdst0 = &b_s[bp][(bq    ) * 64][0];
    u16* bdst1 = &b_s[bp][(bq + 1) * 64][0];

    for (int s0 = 0; s0 < cnt; s0 += 128) {   // typ. one chunk (cnt<=128)
        int i0 = s0 + sr; if (i0 > cnt - 1) i0 = cnt - 1;
        const float* apq = Af + ((size_t)b * 200 + idx_s[i0]) * 256 + sc * 8;

        ffrag zf = {0.f, 0.f, 0.f, 0.f};
        ffrag acc[2][8];
#pragma unroll
        for (int mi = 0; mi < 2; mi++)
#pragma unroll
            for (int ni = 0; ni < 8; ni++) acc[mi][ni] = zf;

        for (int kk = 0; kk < 256; kk += 32) {
            __syncthreads();               // prev readers done
            // B: direct-to-LDS DMA (issued first; flies during A pack)
            gload16(wsrc0 + kk, bdst0);
            gload16(wsrc1 + kk, bdst1);
            // A: f32 gather + RNE pack (unchanged)
            {
                float4 f0 = *(const float4*)(apq + kk);
                float4 f1 = *(const float4*)(apq + kk + 4);
                uint4 va = { pack2bf(f0.x, f0.y), pack2bf(f0.z, f0.w),
                             pack2bf(f1.x, f1.y), pack2bf(f1.z, f1.w) };
                *(uint4*)&a_s[sc][sr ^ (sc << 2)][0] = va;
            }
            __syncthreads();               // tiles ready (vmcnt+lgkm drained)

            bfrag af[2];
#pragma unroll
            for (int mi = 0; mi < 2; mi++) {
                int mm = wm * 32 + mi * 16 + l16;
                af[mi] = *(const bfrag*)&a_s[quad][mm ^ (quad << 2)][0];
            }
#pragma unroll
            for (int ni = 0; ni < 8; ni++) {
                int n = wn * 128 + ni * 16 + l16;
                bfrag bv = *(const bfrag*)&b_s[quad][n ^ (quad << 2)][0];
#pragma unroll
                for (int mi = 0; mi < 2; mi++)
                    acc[mi][ni] = mfma16(af[mi], bv, acc[mi][ni]);
            }
        }

        const float* bias = (matid == 0) ? b0 : (matid == 1) ? b1 : b2;
        u16* dst = (matid == 0) ? o0 : (matid == 1) ? o1 : o2;
#pragma unroll
        for (int ni = 0; ni < 8; ni++) {
            int nloc = wn * 128 + ni * 16 + l16;     // 0..255 within D
            float bb = bias[nloc];
            size_t hbase = (size_t)b * 51200 + (size_t)(nloc >> 4) * 3200 + (nloc & 15);
#pragma unroll
            for (int mi = 0; mi < 2; mi++) {
                int slotb = s0 + wm * 32 + mi * 16 + quad * 4;
#pragma unroll
                for (int r = 0; r < 4; r++) {
                    int slot = slotb + r;
                    if (slot < cnt)
                        dst[hbase + (size_t)slot * 16] = f2bf(acc[mi][ni][r] + bb);
                }
            }
        }
    }
}

// ---------------------------------------------------------------------------
// MHA per (b,h), fully compacted. grid 4096, block 256 (4 waves). Unchanged.
// ---------------------------------------------------------------------------
__global__ __launch_bounds__(256) void attn_k(
    u16* __restrict__ Q, const u16* __restrict__ K,
    const u16* __restrict__ V, const int* __restrict__ msk)
{
    const int blk = blockIdx.x;            // b*16+h
    const int b = blk >> 4;
    const int tid = threadIdx.x;
    const int wave = tid >> 6, lane = tid & 63;
    const int quad = lane >> 4, l16 = lane & 15;
    const size_t sbase = (size_t)blk * 3200;

    const float SL2E = 0.36067376022224085f;   // 0.25 * log2(e)

    __shared__ __align__(8)  u16 kc_s[208][20];   // K slots (cols 0..15 used)
    __shared__ __align__(16) u16 vt_s[16][228];   // V^T [dh][slot]
    __shared__ __align__(16) float am_s[224];     // 0 if i<cnt else -1e30
    __shared__ int wcnt_s[4];

    int m = 0;
    if (tid < 200) m = (msk[b * 200 + tid] != 0) ? 1 : 0;
    u64 bal = __ballot(m);
    if (lane == 0) wcnt_s[wave] = __popcll(bal);
    if (tid < 208) {
        u64* z = (u64*)&kc_s[tid][0];
        z[0] = 0; z[1] = 0; z[2] = 0; z[3] = 0;
    }
    u32* vz = (u32*)&vt_s[0][0];
    for (int i = tid; i < 1824; i += 256) vz[i] = 0;
    __syncthreads();

    int cnt = wcnt_s[0] + wcnt_s[1] + wcnt_s[2] + wcnt_s[3];
    if (cnt == 0) cnt = 200;               // identity fallback (== reference)
    for (int i = tid; i < 224; i += 256)
        am_s[i] = (i < cnt) ? 0.f : -1e30f;
    __syncthreads();

    if (tid < cnt) {
        const u64* ks = (const u64*)(K + sbase + tid * 16);
        u64* kd = (u64*)&kc_s[tid][0];
        kd[0] = ks[0]; kd[1] = ks[1]; kd[2] = ks[2]; kd[3] = ks[3];
        const u16* vp = V + sbase + tid * 16;
        bfrag v0 = *(const bfrag*)vp;
        bfrag v1 = *(const bfrag*)(vp + 8);
#pragma unroll
        for (int j = 0; j < 8; j++) {
            vt_s[j][tid]     = (u16)v0[j];
            vt_s[8 + j][tid] = (u16)v1[j];
        }
    }
    __syncthreads();

    const int nt = (cnt + 15) >> 4;        // active tiles (keys AND queries)

    for (int t = wave; t < nt; t += 4) {
        int lq = t * 16 + l16; if (lq >= cnt) lq = cnt - 1;  // clamp (writes guarded)
        sfrag qf = *(const sfrag*)(Q + sbase + lq * 16 + quad * 4);

        float s[13][4];
#pragma unroll
        for (int kt = 0; kt < 13; kt++) {
            if (kt < nt) {
                sfrag kf = *(const sfrag*)&kc_s[kt * 16 + l16][quad * 4];
                ffrag c = {0.f, 0.f, 0.f, 0.f};
                c = mfma16k16(kf, qf, c);
                ffrag am4 = *(const ffrag*)&am_s[kt * 16 + quad * 4];
#pragma unroll
                for (int r = 0; r < 4; r++)
                    s[kt][r] = __builtin_fmaf(c[r], SL2E, am4[r]);
            }
        }
        float mx = -3e38f;
#pragma unroll
        for (int kt = 0; kt < 13; kt++)
            if (kt < nt)
#pragma unroll
                for (int r = 0; r < 4; r++) mx = fmaxf(mx, s[kt][r]);
        mx = fmaxf(mx, __shfl_xor(mx, 16, 64));
        mx = fmaxf(mx, __shfl_xor(mx, 32, 64));
        float sm = 0.f;
#pragma unroll
        for (int kt = 0; kt < 13; kt++) {
            if (kt < nt) {
                float p0 = __builtin_amdgcn_exp2f(s[kt][0] - mx);
                float p1 = __builtin_amdgcn_exp2f(s[kt][1] - mx);
                float p2 = __builtin_amdgcn_exp2f(s[kt][2] - mx);
                float p3 = __builtin_amdgcn_exp2f(s[kt][3] - mx);
                sm += (p0 + p1) + (p2 + p3);
                s[kt][0] = p0; s[kt][1] = p1; s[kt][2] = p2; s[kt][3] = p3;
            }
        }
        sm += __shfl_xor(sm, 16, 64);
        sm += __shfl_xor(sm, 32, 64);
        float rs = 1.0f / sm;
        ffrag o = {0.f, 0.f, 0.f, 0.f};
#pragma unroll
        for (int kt = 0; kt < 13; kt++) {
            if (kt < nt) {
                union { sfrag v; u32 u[2]; } pk;
                pk.u[0] = pack2bf(s[kt][0] * rs, s[kt][1] * rs);
                pk.u[1] = pack2bf(s[kt][2] * rs, s[kt][3] * rs);
                sfrag bv = *(const sfrag*)&vt_s[l16][kt * 16 + quad * 4];
                o = mfma16k16(pk.v, bv, o);
            }
        }
        int lb = t * 16 + quad * 4;
        u16* qo = Q + sbase + lb * 16 + l16;
#pragma unroll
        for (int r = 0; r < 4; r++) {
            if (lb + r < cnt)
                qo[r * 16] = f2bf(o[r]);   // ctx in-place over Q
        }
    }
}

// ---------------------------------------------------------------------------
// FUSED output projection + query pooling, per batch. grid 256 (1 block/CU),
// block 512 (8 waves). Reg-staged ISSUE-EARLY/WRITE-LATE K-loop (T14).
// The compact news_out tile (<=200x256 bf16, 100 KB) never touches HBM.
// Unchanged from the passing r13 build.
// ---------------------------------------------------------------------------
__global__ __launch_bounds__(512) void projpool_k(
    const u16* __restrict__ ctx,       // head-major compact (qbuf)
    const u16* __restrict__ Wt,        // Wo^T [256][256] bf16
    const float* __restrict__ bo,
    const int* __restrict__ msk,
    const float* __restrict__ qn,
    float* __restrict__ out)
{
    const int b = blockIdx.x;
    const int tid = threadIdx.x;
    const int wave = tid >> 6, lane = tid & 63;
    const int quad = lane >> 4, l16 = lane & 15;
    const int wm = wave >> 1, wn = wave & 1;   // 4x2 wave grid

    __shared__ __align__(16) u16 no_s[200][256];    // 100 KB news_out tile
    __shared__ __align__(16) u16 a_s[4][128][8];    //   8 KB
    __shared__ __align__(16) u16 b_s[4][256][8];    //  16 KB
    __shared__ float q_sh[256];
    __shared__ float s_sh[200];
    __shared__ float p_sh[200];
    __shared__ float red_s[16];
    __shared__ float part_s[8][256];                //   8 KB
    __shared__ int wcnt_s[8];

    // ---- ballot (cnt only; ctx already compact)
    int m = 0;
    if (tid < 200) m = (msk[b * 200 + tid] != 0) ? 1 : 0;
    u64 bal = __ballot(m);
    if (lane == 0) wcnt_s[wave] = __popcll(bal);
    if (tid < 256) q_sh[tid] = qn[tid];
    __syncthreads();
    int cnt = 0;
#pragma unroll
    for (int w = 0; w < 8; w++) cnt += wcnt_s[w];
    const bool allm = (cnt == 0);
    if (allm) cnt = 200;

    // ---- proj GEMM into LDS tile (issue-early/write-late pipeline)
    const int sr = tid >> 2;               // 0..127
    const int sc = tid & 3;                // k-octet 0..3
    const u16* Wp = Wt + (size_t)sr * 256 + sc * 8;

    for (int s0 = 0; s0 < cnt; s0 += 128) {
        int sl = s0 + sr; if (sl > cnt - 1) sl = cnt - 1;
        const u16* apj = ctx + (size_t)b * 51200 + sl * 16;

        ffrag zf = {0.f, 0.f, 0.f, 0.f};
        ffrag acc[2][8];
#pragma unroll
        for (int mi = 0; mi < 2; mi++)
#pragma unroll
            for (int ni = 0; ni < 8; ni++) acc[mi][ni] = zf;

        // preload k-step 0 into regs
        bfrag aR, bR0, bR1;
        {
            int c = sc * 8;
            size_t hofs = (size_t)(c >> 4) * 3200 + (c & 8);
            aR  = *(const bfrag*)(apj + hofs);
            bR0 = *(const bfrag*)(Wp);
            bR1 = *(const bfrag*)(Wp + (size_t)128 * 256);
        }

        for (int kk = 0; kk < 256; kk += 32) {
            // write-late: current step's regs -> LDS (prev readers are done:
            // barrier at the end of the previous iteration)
            *(bfrag*)&a_s[sc][sr ^ (sc << 2)][0]          = aR;
            *(bfrag*)&b_s[sc][sr ^ (sc << 2)][0]          = bR0;
            *(bfrag*)&b_s[sc][(sr + 128) ^ (sc << 2)][0]  = bR1;
            __syncthreads();               // tile kk ready

            // issue-early: next step's loads, in flight during MFMA phase
            if (kk < 224) {
                int c = kk + 32 + sc * 8;
                size_t hofs = (size_t)(c >> 4) * 3200 + (c & 8);
                aR  = *(const bfrag*)(apj + hofs);
                bR0 = *(const bfrag*)(Wp + kk + 32);
                bR1 = *(const bfrag*)(Wp + (size_t)128 * 256 + kk + 32);
            }

            bfrag af[2];
#pragma unroll
            for (int mi = 0; mi < 2; mi++) {
                int mm = wm * 32 + mi * 16 + l16;
                af[mi] = *(const bfrag*)&a_s[quad][mm ^ (quad << 2)][0];
            }
#pragma unroll
            for (int ni = 0; ni < 8; ni++) {
                int n = wn * 128 + ni * 16 + l16;
                bfrag bv = *(const bfrag*)&b_s[quad][n ^ (quad << 2)][0];
#pragma unroll
                for (int mi = 0; mi < 2; mi++)
                    acc[mi][ni] = mfma16(af[mi], bv, acc[mi][ni]);
            }
            __syncthreads();               // readers done; safe to overwrite
        }

#pragma unroll
        for (int ni = 0; ni < 8; ni++) {
            int col = wn * 128 + ni * 16 + l16;
            float bb = bo[col];
#pragma unroll
            for (int mi = 0; mi < 2; mi++) {
                int slotb = s0 + wm * 32 + mi * 16 + quad * 4;
#pragma unroll
                for (int r = 0; r < 4; r++) {
                    int slot = slotb + r;
                    if (slot < cnt)
                        no_s[slot][col] = f2bf(acc[mi][ni][r] + bb);
                }
            }
        }
    }
    __syncthreads();                       // tile complete

    // ---- pool phase 1: s_l = dot(no_s[l], q) / 16 — wave-per-slot
    for (int l = wave; l < cnt; l += 8) {
        u64 v = *(const u64*)&no_s[l][lane * 4];
        float d = bf2f((u16)v)         * q_sh[lane * 4 + 0]
                + bf2f((u16)(v >> 16)) * q_sh[lane * 4 + 1]
                + bf2f((u16)(v >> 32)) * q_sh[lane * 4 + 2]
                + bf2f((u16)(v >> 48)) * q_sh[lane * 4 + 3];
#pragma unroll
        for (int dd = 1; dd < 64; dd <<= 1) d += __shfl_xor(d, dd, 64);
        if (lane == 0) s_sh[l] = d * 0.0625f;
    }
    __syncthreads();

    // ---- softmax over cnt compact slots
    float s = -1e30f;
    if (tid < cnt) s = allm ? -1e9f : s_sh[tid];
    float mw = s;
#pragma unroll
    for (int dd = 1; dd < 64; dd <<= 1) mw = fmaxf(mw, __shfl_xor(mw, dd, 64));
    if (lane == 0) red_s[wave] = mw;
    __syncthreads();
    float mmax = red_s[0];
#pragma unroll
    for (int w = 1; w < 8; w++) mmax = fmaxf(mmax, red_s[w]);
    float e = (tid < cnt) ? __expf(s - mmax) : 0.f;
    float sw = e;
#pragma unroll
    for (int dd = 1; dd < 64; dd <<= 1) sw += __shfl_xor(sw, dd, 64);
    if (lane == 0) red_s[8 + wave] = sw;
    __syncthreads();
    float ssum = 0.f;
#pragma unroll
    for (int w = 0; w < 8; w++) ssum += red_s[8 + w];
    if (tid < cnt) p_sh[tid] = e / ssum;
    __syncthreads();

    // ---- pool phase 2: out[d] = sum_l p_l * no_s[l][d]
    float a0 = 0.f, a1 = 0.f, a2 = 0.f, a3 = 0.f;
    for (int l = wave; l < cnt; l += 8) {
        float p = p_sh[l];
        u64 v = *(const u64*)&no_s[l][lane * 4];
        a0 += p * bf2f((u16)v);
        a1 += p * bf2f((u16)(v >> 16));
        a2 += p * bf2f((u16)(v >> 32));
        a3 += p * bf2f((u16)(v >> 48));
    }
    part_s[wave][lane * 4 + 0] = a0;
    part_s[wave][lane * 4 + 1] = a1;
    part_s[wave][lane * 4 + 2] = a2;
    part_s[wave][lane * 4 + 3] = a3;
    __syncthreads();
    if (tid < 256) {
        float t = 0.f;
#pragma unroll
        for (int w = 0; w < 8; w++) t += part_s[w][tid];
        out[(size_t)b * 256 + tid] = t;
    }
}

// ---------------------------------------------------------------------------
extern "C" void kernel_launch(void* const* d_in, const int* in_sizes, int n_in,
                              void* d_out, int out_size, void* d_ws, size_t ws_size,
                              hipStream_t stream) {
    const float* X   = (const float*)d_in[0];
    const int*   msk = (const int*)d_in[1];
    const float* Wq  = (const float*)d_in[2];
    const float* bq  = (const float*)d_in[3];
    const float* Wk  = (const float*)d_in[4];
    const float* bk  = (const float*)d_in[5];
    const float* Wv  = (const float*)d_in[6];
    const float* bv  = (const float*)d_in[7];
    const float* Wo  = (const float*)d_in[8];
    const float* bo  = (const float*)d_in[9];
    const float* qn  = (const float*)d_in[10];
    float* out = (float*)d_out;

    // ws layout (79,167,488 B):
    //   qbuf: Q head-major compact -> ctx in-place     26,214,400
    //   kbuf: K head-major compact                     26,214,400
    //   vbuf: V head-major compact                     26,214,400
    //   wt:   [1024][256] bf16 weights^T                  524,288
    char* ws = (char*)d_ws;
    u16* qbuf = (u16*)(ws);
    u16* kbuf = (u16*)(ws + 26214400);
    u16* vbuf = (u16*)(ws + 52428800);
    u16* wt   = (u16*)(ws + 78643200);

    wtrans_k<<<dim3(4, 4, 4), 256, 0, stream>>>(Wq, Wk, Wv, Wo, wt);

    gemm_k<<<dim3(256, 3), 512, 0, stream>>>(
        X, wt, msk, bq, bk, bv, qbuf, kbuf, vbuf);

    attn_k<<<4096, 256, 0, stream>>>(qbuf, kbuf, vbuf, msk);

    projpool_k<<<256, 512, 0, stream>>>(
        qbuf, wt + 196608, bo, msk, qn, out);
}

// Round 16
// 177.878 us; speedup vs baseline: 1.0726x; 1.0726x over previous
//
#include <hip/hip_runtime.h>

typedef unsigned short u16;
typedef unsigned int u32;
typedef unsigned long long u64;
typedef __attribute__((ext_vector_type(8))) short bfrag;  // 8 bf16 (4 VGPRs)
typedef __attribute__((ext_vector_type(4))) short sfrag;  // 4 bf16 (2 VGPRs)
typedef __attribute__((ext_vector_type(4))) float ffrag;  // 4 fp32

// B=256, L=200, D=256, H=16, Dh=16, M=51200
// Head-major slice: [B,H,slot,16], slice stride 3200 u16, b-stride 51200 u16.
// COMPACT convention: per batch b, slot i (i<cnt_b) = i-th UNMASKED l
// (ascending). cnt_b==0 -> identity map over all 200 (matches reference's
// shift-invariant softmax / uniform pool). Slots >= cnt_b are never written;
// reads are clamped to slot<cnt so uninitialized memory never propagates.
//
// FINAL build (r16): r13 configuration, measured best passing @178.7 us.
// Rejected variants: BK=64 (r12, replay race), gload_lds B-staging (r15,
// 43->55 us: 16 wave-serial DMAs lose to 128 distributed loads in the
// short 2-barrier window).

__device__ __forceinline__ float bf2f(u16 u) {
    union { float f; u32 i; } c; c.i = ((u32)u) << 16; return c.f;
}
__device__ __forceinline__ u16 f2bf(float f) {           // RNE
    union { float f; u32 i; } c; c.f = f;
    u32 r = c.i + 0x7FFFu + ((c.i >> 16) & 1u);
    return (u16)(r >> 16);
}
__device__ __forceinline__ u32 pack2bf(float lo, float hi) {  // RNE pair
    union { float f; u32 i; } a, b; a.f = lo; b.f = hi;
    u32 ra = a.i + 0x7FFFu + ((a.i >> 16) & 1u);
    u32 rb = b.i + 0x7FFFu + ((b.i >> 16) & 1u);
    return (ra >> 16) | (rb & 0xFFFF0000u);
}
__device__ __forceinline__ ffrag mfma16(bfrag a, bfrag b, ffrag c) {
    return __builtin_amdgcn_mfma_f32_16x16x32_bf16(a, b, c, 0, 0, 0);
}
__device__ __forceinline__ ffrag mfma16k16(sfrag a, sfrag b, ffrag c) {
    return __builtin_amdgcn_mfma_f32_16x16x16bf16_1k(a, b, c, 0, 0, 0);
}

// ---------------------------------------------------------------------------
// LDS-tiled transpose+cast: W[k][n] f32 -> Wt[n][k] bf16, 4 matrices.
// ---------------------------------------------------------------------------
__global__ __launch_bounds__(256) void wtrans_k(
    const float* __restrict__ W0, const float* __restrict__ W1,
    const float* __restrict__ W2, const float* __restrict__ W3,
    u16* __restrict__ Wt)
{
    __shared__ u16 t_s[64][72];
    const int mat = blockIdx.z;
    const float* W = (mat == 0) ? W0 : (mat == 1) ? W1 : (mat == 2) ? W2 : W3;
    const int k0 = blockIdx.x * 64, n0 = blockIdx.y * 64;
    const int r = threadIdx.x >> 2, cq = threadIdx.x & 3;

    const float* src = W + (size_t)(k0 + r) * 256 + n0 + cq * 16;
#pragma unroll
    for (int j = 0; j < 16; j += 4) {
        float4 f = *(const float4*)(src + j);
        t_s[cq * 16 + j + 0][r] = f2bf(f.x);
        t_s[cq * 16 + j + 1][r] = f2bf(f.y);
        t_s[cq * 16 + j + 2][r] = f2bf(f.z);
        t_s[cq * 16 + j + 3][r] = f2bf(f.w);
    }
    __syncthreads();
    u16* dst = Wt + ((size_t)mat * 256 + n0 + r) * 256 + k0 + cq * 16;
    *(bfrag*)(dst)     = *(const bfrag*)&t_s[r][cq * 16];
    *(bfrag*)(dst + 8) = *(const bfrag*)&t_s[r][cq * 16 + 8];
}

// ---------------------------------------------------------------------------
// GEMM v9 (proven r8-r13, final): 512-thread block, tile 128(M) x 256(N).
// 8 waves in 4(M) x 2(N): wave tile 32x128, acc[2][8] = 64 AGPR.
// r0-proven single-buffer BK=32 2-barrier loop + XOR swizzle.
// grid (256, 3). Chunk loop handles cnt>128.
// ---------------------------------------------------------------------------
__global__ __launch_bounds__(512) void gemm_k(
    const void* __restrict__ Avp, const u16* __restrict__ Wtp,
    const int* __restrict__ msk,
    const float* __restrict__ b0, const float* __restrict__ b1,
    const float* __restrict__ b2,
    u16* __restrict__ o0, u16* __restrict__ o1, u16* __restrict__ o2)
{
    const int b     = blockIdx.x;          // 0..255
    const int matid = blockIdx.y;          // 0=Q 1=K 2=V
    const int tid = threadIdx.x;
    const int wave = tid >> 6, lane = tid & 63;
    const int quad = lane >> 4, l16 = lane & 15;
    const int wm = wave >> 1, wn = wave & 1;   // 4x2 wave grid

    __shared__ __align__(16) u16 a_s[4][128][8];   //  8 KB
    __shared__ __align__(16) u16 b_s[4][256][8];   // 16 KB
    __shared__ u16 idx_s[200];
    __shared__ int wcnt_s[8];

    int m = 0;
    if (tid < 200) m = (msk[b * 200 + tid] != 0) ? 1 : 0;
    u64 bal = __ballot(m);
    if (lane == 0) wcnt_s[wave] = __popcll(bal);
    __syncthreads();
    int cnt = 0;
#pragma unroll
    for (int w = 0; w < 8; w++) cnt += wcnt_s[w];
    if (cnt == 0) {
        if (tid < 200) idx_s[tid] = (u16)tid;
    } else if (m) {
        int woff = 0;
        for (int w = 0; w < wave; w++) woff += wcnt_s[w];
        idx_s[woff + __popcll(bal & ((1ull << lane) - 1ull))] = (u16)tid;
    }
    __syncthreads();
    if (cnt == 0) cnt = 200;

    const float* Af = (const float*)Avp;

    const int sr = tid >> 2;               // 0..127
    const int sc = tid & 3;                // k-octet 0..3
    const u16* Wp = Wtp + (size_t)(matid * 256 + sr) * 256 + sc * 8;

    for (int s0 = 0; s0 < cnt; s0 += 128) {   // typ. one chunk (cnt<=128)
        int i0 = s0 + sr; if (i0 > cnt - 1) i0 = cnt - 1;
        const float* apq = Af + ((size_t)b * 200 + idx_s[i0]) * 256 + sc * 8;

        ffrag zf = {0.f, 0.f, 0.f, 0.f};
        ffrag acc[2][8];
#pragma unroll
        for (int mi = 0; mi < 2; mi++)
#pragma unroll
            for (int ni = 0; ni < 8; ni++) acc[mi][ni] = zf;

        for (int kk = 0; kk < 256; kk += 32) {
            __syncthreads();               // prev readers done
            {
                float4 f0 = *(const float4*)(apq + kk);
                float4 f1 = *(const float4*)(apq + kk + 4);
                uint4 va = { pack2bf(f0.x, f0.y), pack2bf(f0.z, f0.w),
                             pack2bf(f1.x, f1.y), pack2bf(f1.z, f1.w) };
                *(uint4*)&a_s[sc][sr ^ (sc << 2)][0] = va;
            }
#pragma unroll
            for (int j = 0; j < 2; j++) {
                int n = sr + j * 128;
                *(bfrag*)&b_s[sc][n ^ (sc << 2)][0] =
                    *(const bfrag*)(Wp + (size_t)j * 128 * 256 + kk);
            }
            __syncthreads();               // tiles ready

            bfrag af[2];
#pragma unroll
            for (int mi = 0; mi < 2; mi++) {
                int mm = wm * 32 + mi * 16 + l16;
                af[mi] = *(const bfrag*)&a_s[quad][mm ^ (quad << 2)][0];
            }
#pragma unroll
            for (int ni = 0; ni < 8; ni++) {
                int n = wn * 128 + ni * 16 + l16;
                bfrag bv = *(const bfrag*)&b_s[quad][n ^ (quad << 2)][0];
#pragma unroll
                for (int mi = 0; mi < 2; mi++)
                    acc[mi][ni] = mfma16(af[mi], bv, acc[mi][ni]);
            }
        }

        const float* bias = (matid == 0) ? b0 : (matid == 1) ? b1 : b2;
        u16* dst = (matid == 0) ? o0 : (matid == 1) ? o1 : o2;
#pragma unroll
        for (int ni = 0; ni < 8; ni++) {
            int nloc = wn * 128 + ni * 16 + l16;     // 0..255 within D
            float bb = bias[nloc];
            size_t hbase = (size_t)b * 51200 + (size_t)(nloc >> 4) * 3200 + (nloc & 15);
#pragma unroll
            for (int mi = 0; mi < 2; mi++) {
                int slotb = s0 + wm * 32 + mi * 16 + quad * 4;
#pragma unroll
                for (int r = 0; r < 4; r++) {
                    int slot = slotb + r;
                    if (slot < cnt)
                        dst[hbase + (size_t)slot * 16] = f2bf(acc[mi][ni][r] + bb);
                }
            }
        }
    }
}

// ---------------------------------------------------------------------------
// MHA per (b,h), fully compacted. grid 4096, block 256 (4 waves). Unchanged.
// ---------------------------------------------------------------------------
__global__ __launch_bounds__(256) void attn_k(
    u16* __restrict__ Q, const u16* __restrict__ K,
    const u16* __restrict__ V, const int* __restrict__ msk)
{
    const int blk = blockIdx.x;            // b*16+h
    const int b = blk >> 4;
    const int tid = threadIdx.x;
    const int wave = tid >> 6, lane = tid & 63;
    const int quad = lane >> 4, l16 = lane & 15;
    const size_t sbase = (size_t)blk * 3200;

    const float SL2E = 0.36067376022224085f;   // 0.25 * log2(e)

    __shared__ __align__(8)  u16 kc_s[208][20];   // K slots (cols 0..15 used)
    __shared__ __align__(16) u16 vt_s[16][228];   // V^T [dh][slot]
    __shared__ __align__(16) float am_s[224];     // 0 if i<cnt else -1e30
    __shared__ int wcnt_s[4];

    int m = 0;
    if (tid < 200) m = (msk[b * 200 + tid] != 0) ? 1 : 0;
    u64 bal = __ballot(m);
    if (lane == 0) wcnt_s[wave] = __popcll(bal);
    if (tid < 208) {
        u64* z = (u64*)&kc_s[tid][0];
        z[0] = 0; z[1] = 0; z[2] = 0; z[3] = 0;
    }
    u32* vz = (u32*)&vt_s[0][0];
    for (int i = tid; i < 1824; i += 256) vz[i] = 0;
    __syncthreads();

    int cnt = wcnt_s[0] + wcnt_s[1] + wcnt_s[2] + wcnt_s[3];
    if (cnt == 0) cnt = 200;               // identity fallback (== reference)
    for (int i = tid; i < 224; i += 256)
        am_s[i] = (i < cnt) ? 0.f : -1e30f;
    __syncthreads();

    if (tid < cnt) {
        const u64* ks = (const u64*)(K + sbase + tid * 16);
        u64* kd = (u64*)&kc_s[tid][0];
        kd[0] = ks[0]; kd[1] = ks[1]; kd[2] = ks[2]; kd[3] = ks[3];
        const u16* vp = V + sbase + tid * 16;
        bfrag v0 = *(const bfrag*)vp;
        bfrag v1 = *(const bfrag*)(vp + 8);
#pragma unroll
        for (int j = 0; j < 8; j++) {
            vt_s[j][tid]     = (u16)v0[j];
            vt_s[8 + j][tid] = (u16)v1[j];
        }
    }
    __syncthreads();

    const int nt = (cnt + 15) >> 4;        // active tiles (keys AND queries)

    for (int t = wave; t < nt; t += 4) {
        int lq = t * 16 + l16; if (lq >= cnt) lq = cnt - 1;  // clamp (writes guarded)
        sfrag qf = *(const sfrag*)(Q + sbase + lq * 16 + quad * 4);

        float s[13][4];
#pragma unroll
        for (int kt = 0; kt < 13; kt++) {
            if (kt < nt) {
                sfrag kf = *(const sfrag*)&kc_s[kt * 16 + l16][quad * 4];
                ffrag c = {0.f, 0.f, 0.f, 0.f};
                c = mfma16k16(kf, qf, c);
                ffrag am4 = *(const ffrag*)&am_s[kt * 16 + quad * 4];
#pragma unroll
                for (int r = 0; r < 4; r++)
                    s[kt][r] = __builtin_fmaf(c[r], SL2E, am4[r]);
            }
        }
        float mx = -3e38f;
#pragma unroll
        for (int kt = 0; kt < 13; kt++)
            if (kt < nt)
#pragma unroll
                for (int r = 0; r < 4; r++) mx = fmaxf(mx, s[kt][r]);
        mx = fmaxf(mx, __shfl_xor(mx, 16, 64));
        mx = fmaxf(mx, __shfl_xor(mx, 32, 64));
        float sm = 0.f;
#pragma unroll
        for (int kt = 0; kt < 13; kt++) {
            if (kt < nt) {
                float p0 = __builtin_amdgcn_exp2f(s[kt][0] - mx);
                float p1 = __builtin_amdgcn_exp2f(s[kt][1] - mx);
                float p2 = __builtin_amdgcn_exp2f(s[kt][2] - mx);
                float p3 = __builtin_amdgcn_exp2f(s[kt][3] - mx);
                sm += (p0 + p1) + (p2 + p3);
                s[kt][0] = p0; s[kt][1] = p1; s[kt][2] = p2; s[kt][3] = p3;
            }
        }
        sm += __shfl_xor(sm, 16, 64);
        sm += __shfl_xor(sm, 32, 64);
        float rs = 1.0f / sm;
        ffrag o = {0.f, 0.f, 0.f, 0.f};
#pragma unroll
        for (int kt = 0; kt < 13; kt++) {
            if (kt < nt) {
                union { sfrag v; u32 u[2]; } pk;
                pk.u[0] = pack2bf(s[kt][0] * rs, s[kt][1] * rs);
                pk.u[1] = pack2bf(s[kt][2] * rs, s[kt][3] * rs);
                sfrag bv = *(const sfrag*)&vt_s[l16][kt * 16 + quad * 4];
                o = mfma16k16(pk.v, bv, o);
            }
        }
        int lb = t * 16 + quad * 4;
        u16* qo = Q + sbase + lb * 16 + l16;
#pragma unroll
        for (int r = 0; r < 4; r++) {
            if (lb + r < cnt)
                qo[r * 16] = f2bf(o[r]);   // ctx in-place over Q
        }
    }
}

// ---------------------------------------------------------------------------
// FUSED output projection + query pooling, per batch. grid 256 (1 block/CU),
// block 512 (8 waves). Reg-staged ISSUE-EARLY/WRITE-LATE K-loop (T14).
// The compact news_out tile (<=200x256 bf16, 100 KB) never touches HBM.
// ---------------------------------------------------------------------------
__global__ __launch_bounds__(512) void projpool_k(
    const u16* __restrict__ ctx,       // head-major compact (qbuf)
    const u16* __restrict__ Wt,        // Wo^T [256][256] bf16
    const float* __restrict__ bo,
    const int* __restrict__ msk,
    const float* __restrict__ qn,
    float* __restrict__ out)
{
    const int b = blockIdx.x;
    const int tid = threadIdx.x;
    const int wave = tid >> 6, lane = tid & 63;
    const int quad = lane >> 4, l16 = lane & 15;
    const int wm = wave >> 1, wn = wave & 1;   // 4x2 wave grid

    __shared__ __align__(16) u16 no_s[200][256];    // 100 KB news_out tile
    __shared__ __align__(16) u16 a_s[4][128][8];    //   8 KB
    __shared__ __align__(16) u16 b_s[4][256][8];    //  16 KB
    __shared__ float q_sh[256];
    __shared__ float s_sh[200];
    __shared__ float p_sh[200];
    __shared__ float red_s[16];
    __shared__ float part_s[8][256];                //   8 KB
    __shared__ int wcnt_s[8];

    // ---- ballot (cnt only; ctx already compact)
    int m = 0;
    if (tid < 200) m = (msk[b * 200 + tid] != 0) ? 1 : 0;
    u64 bal = __ballot(m);
    if (lane == 0) wcnt_s[wave] = __popcll(bal);
    if (tid < 256) q_sh[tid] = qn[tid];
    __syncthreads();
    int cnt = 0;
#pragma unroll
    for (int w = 0; w < 8; w++) cnt += wcnt_s[w];
    const bool allm = (cnt == 0);
    if (allm) cnt = 200;

    // ---- proj GEMM into LDS tile (issue-early/write-late pipeline)
    const int sr = tid >> 2;               // 0..127
    const int sc = tid & 3;                // k-octet 0..3
    const u16* Wp = Wt + (size_t)sr * 256 + sc * 8;

    for (int s0 = 0; s0 < cnt; s0 += 128) {
        int sl = s0 + sr; if (sl > cnt - 1) sl = cnt - 1;
        const u16* apj = ctx + (size_t)b * 51200 + sl * 16;

        ffrag zf = {0.f, 0.f, 0.f, 0.f};
        ffrag acc[2][8];
#pragma unroll
        for (int mi = 0; mi < 2; mi++)
#pragma unroll
            for (int ni = 0; ni < 8; ni++) acc[mi][ni] = zf;

        // preload k-step 0 into regs
        bfrag aR, bR0, bR1;
        {
            int c = sc * 8;
            size_t hofs = (size_t)(c >> 4) * 3200 + (c & 8);
            aR  = *(const bfrag*)(apj + hofs);
            bR0 = *(const bfrag*)(Wp);
            bR1 = *(const bfrag*)(Wp + (size_t)128 * 256);
        }

        for (int kk = 0; kk < 256; kk += 32) {
            // write-late: current step's regs -> LDS (prev readers are done:
            // barrier at the end of the previous iteration)
            *(bfrag*)&a_s[sc][sr ^ (sc << 2)][0]          = aR;
            *(bfrag*)&b_s[sc][sr ^ (sc << 2)][0]          = bR0;
            *(bfrag*)&b_s[sc][(sr + 128) ^ (sc << 2)][0]  = bR1;
            __syncthreads();               // tile kk ready

            // issue-early: next step's loads, in flight during MFMA phase
            if (kk < 224) {
                int c = kk + 32 + sc * 8;
                size_t hofs = (size_t)(c >> 4) * 3200 + (c & 8);
                aR  = *(const bfrag*)(apj + hofs);
                bR0 = *(const bfrag*)(Wp + kk + 32);
                bR1 = *(const bfrag*)(Wp + (size_t)128 * 256 + kk + 32);
            }

            bfrag af[2];
#pragma unroll
            for (int mi = 0; mi < 2; mi++) {
                int mm = wm * 32 + mi * 16 + l16;
                af[mi] = *(const bfrag*)&a_s[quad][mm ^ (quad << 2)][0];
            }
#pragma unroll
            for (int ni = 0; ni < 8; ni++) {
                int n = wn * 128 + ni * 16 + l16;
                bfrag bv = *(const bfrag*)&b_s[quad][n ^ (quad << 2)][0];
#pragma unroll
                for (int mi = 0; mi < 2; mi++)
                    acc[mi][ni] = mfma16(af[mi], bv, acc[mi][ni]);
            }
            __syncthreads();               // readers done; safe to overwrite
        }

#pragma unroll
        for (int ni = 0; ni < 8; ni++) {
            int col = wn * 128 + ni * 16 + l16;
            float bb = bo[col];
#pragma unroll
            for (int mi = 0; mi < 2; mi++) {
                int slotb = s0 + wm * 32 + mi * 16 + quad * 4;
#pragma unroll
                for (int r = 0; r < 4; r++) {
                    int slot = slotb + r;
                    if (slot < cnt)
                        no_s[slot][col] = f2bf(acc[mi][ni][r] + bb);
                }
            }
        }
    }
    __syncthreads();                       // tile complete

    // ---- pool phase 1: s_l = dot(no_s[l], q) / 16 — wave-per-slot
    for (int l = wave; l < cnt; l += 8) {
        u64 v = *(const u64*)&no_s[l][lane * 4];
        float d = bf2f((u16)v)         * q_sh[lane * 4 + 0]
                + bf2f((u16)(v >> 16)) * q_sh[lane * 4 + 1]
                + bf2f((u16)(v >> 32)) * q_sh[lane * 4 + 2]
                + bf2f((u16)(v >> 48)) * q_sh[lane * 4 + 3];
#pragma unroll
        for (int dd = 1; dd < 64; dd <<= 1) d += __shfl_xor(d, dd, 64);
        if (lane == 0) s_sh[l] = d * 0.0625f;
    }
    __syncthreads();

    // ---- softmax over cnt compact slots
    float s = -1e30f;
    if (tid < cnt) s = allm ? -1e9f : s_sh[tid];
    float mw = s;
#pragma unroll
    for (int dd = 1; dd < 64; dd <<= 1) mw = fmaxf(mw, __shfl_xor(mw, dd, 64));
    if (lane == 0) red_s[wave] = mw;
    __syncthreads();
    float mmax = red_s[0];
#pragma unroll
    for (int w = 1; w < 8; w++) mmax = fmaxf(mmax, red_s[w]);
    float e = (tid < cnt) ? __expf(s - mmax) : 0.f;
    float sw = e;
#pragma unroll
    for (int dd = 1; dd < 64; dd <<= 1) sw += __shfl_xor(sw, dd, 64);
    if (lane == 0) red_s[8 + wave] = sw;
    __syncthreads();
    float ssum = 0.f;
#pragma unroll
    for (int w = 0; w < 8; w++) ssum += red_s[8 + w];
    if (tid < cnt) p_sh[tid] = e / ssum;
    __syncthreads();

    // ---- pool phase 2: out[d] = sum_l p_l * no_s[l][d]
    float a0 = 0.f, a1 = 0.f, a2 = 0.f, a3 = 0.f;
    for (int l = wave; l < cnt; l += 8) {
        float p = p_sh[l];
        u64 v = *(const u64*)&no_s[l][lane * 4];
        a0 += p * bf2f((u16)v);
        a1 += p * bf2f((u16)(v >> 16));
        a2 += p * bf2f((u16)(v >> 32));
        a3 += p * bf2f((u16)(v >> 48));
    }
    part_s[wave][lane * 4 + 0] = a0;
    part_s[wave][lane * 4 + 1] = a1;
    part_s[wave][lane * 4 + 2] = a2;
    part_s[wave][lane * 4 + 3] = a3;
    __syncthreads();
    if (tid < 256) {
        float t = 0.f;
#pragma unroll
        for (int w = 0; w < 8; w++) t += part_s[w][tid];
        out[(size_t)b * 256 + tid] = t;
    }
}

// ---------------------------------------------------------------------------
extern "C" void kernel_launch(void* const* d_in, const int* in_sizes, int n_in,
                              void* d_out, int out_size, void* d_ws, size_t ws_size,
                              hipStream_t stream) {
    const float* X   = (const float*)d_in[0];
    const int*   msk = (const int*)d_in[1];
    const float* Wq  = (const float*)d_in[2];
    const float* bq  = (const float*)d_in[3];
    const float* Wk  = (const float*)d_in[4];
    const float* bk  = (const float*)d_in[5];
    const float* Wv  = (const float*)d_in[6];
    const float* bv  = (const float*)d_in[7];
    const float* Wo  = (const float*)d_in[8];
    const float* bo  = (const float*)d_in[9];
    const float* qn  = (const float*)d_in[10];
    float* out = (float*)d_out;

    // ws layout (79,167,488 B):
    //   qbuf: Q head-major compact -> ctx in-place     26,214,400
    //   kbuf: K head-major compact                     26,214,400
    //   vbuf: V head-major compact                     26,214,400
    //   wt:   [1024][256] bf16 weights^T                  524,288
    char* ws = (char*)d_ws;
    u16* qbuf = (u16*)(ws);
    u16* kbuf = (u16*)(ws + 26214400);
    u16* vbuf = (u16*)(ws + 52428800);
    u16* wt   = (u16*)(ws + 78643200);

    wtrans_k<<<dim3(4, 4, 4), 256, 0, stream>>>(Wq, Wk, Wv, Wo, wt);

    gemm_k<<<dim3(256, 3), 512, 0, stream>>>(
        X, wt, msk, bq, bk, bv, qbuf, kbuf, vbuf);

    attn_k<<<4096, 256, 0, stream>>>(qbuf, kbuf, vbuf, msk);

    projpool_k<<<256, 512, 0, stream>>>(
        qbuf, wt + 196608, bo, msk, qn, out);
}